// Round 4
// baseline (965.157 us; speedup 1.0000x reference)
//
#include <hip/hip_runtime.h>
#include <stdint.h>

#define B_    16
#define N_    65536
#define NPTS  (B_*N_)
#define NBK   11
#define NFEAT 259
#define NF    ((float)NPTS)

typedef float f32x4 __attribute__((ext_vector_type(4)));
typedef short s16x8 __attribute__((ext_vector_type(8)));

// ---- workspace float offsets ----
enum {
  OFF_YMINF = 16,     // 16
  OFF_YMAXF = 32,     // 16
  OFF_A1    = 64,     // 64
  OFF_C1    = 128,    // 64
  OFF_A2    = 192,    // 128
  OFF_C2    = 320,    // 128
  OFF_CX    = 448,    // 176
  OFF_CZ    = 624,    // 176
  OFF_A3    = 800,    // 256
  OFF_C3    = 1056,   // 256
  // per-block partials (512 blocks)
  OFF_PSTR  = 16384,  // 512*16 : s0,s1,s2,q00,q01,q02,q11,q12,q22,ymn,ymx
  OFF_PBKT  = 24576,  // 512*36 : sx[11], sz[11], cnt[11]
  OFF_PH2   = 49152,  // 512*256: sum[128], sq[128]
  OFF_PH3   = 180224, // 512*512: sum[256], sq[256]
  OFF_PPOOL = 442368, // 512*512: max[256], sum[256]
  OFF_PSPA  = 704512  // 512*8  : max[3], sum[3]
};

// ---- helpers ----
__device__ __forceinline__ float wave_sum(float v){
  #pragma unroll
  for (int m=32;m>=1;m>>=1) v += __shfl_xor(v,m,64);
  return v;
}
__device__ __forceinline__ float wave_max(float v){
  #pragma unroll
  for (int m=32;m>=1;m>>=1) v = fmaxf(v,__shfl_xor(v,m,64));
  return v;
}
__device__ __forceinline__ float wave_min(float v){
  #pragma unroll
  for (int m=32;m>=1;m>>=1) v = fminf(v,__shfl_xor(v,m,64));
  return v;
}
__device__ __forceinline__ unsigned short bf16_bits(float f){
  unsigned u=__float_as_uint(f);
  u += 0x7FFFu + ((u>>16)&1u);
  return (unsigned short)(u>>16);
}

// ---- pass A: x colsums + X^T X + per-batch y min/max -> per-block partials ----
__global__ __launch_bounds__(256) void k_stream0(const float* __restrict__ x,
                                                 float* __restrict__ ws){
  __shared__ float red[4][12];
  const int t=threadIdx.x, l=t&63, w=t>>6;
  const int bid=blockIdx.x;
  const float4* xv=(const float4*)(x + (size_t)bid*2048*3);
  float s0=0,s1=0,s2=0,q00=0,q01=0,q02=0,q11=0,q12=0,q22=0;
  float ymn=3.4e38f, ymx=-3.4e38f;
  #pragma unroll
  for (int i=0;i<2;i++){
    const int vi=(i*256+t)*3;
    const float4 a=xv[vi], b4=xv[vi+1], c=xv[vi+2];
    float X[4]={a.x,a.w,b4.z,c.y};
    float Y[4]={a.y,b4.x,b4.w,c.z};
    float Z[4]={a.z,b4.y,c.x,c.w};
    #pragma unroll
    for (int p=0;p<4;p++){
      s0+=X[p]; s1+=Y[p]; s2+=Z[p];
      q00=fmaf(X[p],X[p],q00); q01=fmaf(X[p],Y[p],q01); q02=fmaf(X[p],Z[p],q02);
      q11=fmaf(Y[p],Y[p],q11); q12=fmaf(Y[p],Z[p],q12); q22=fmaf(Z[p],Z[p],q22);
      ymn=fminf(ymn,Y[p]); ymx=fmaxf(ymx,Y[p]);
    }
  }
  s0=wave_sum(s0); s1=wave_sum(s1); s2=wave_sum(s2);
  q00=wave_sum(q00); q01=wave_sum(q01); q02=wave_sum(q02);
  q11=wave_sum(q11); q12=wave_sum(q12); q22=wave_sum(q22);
  ymn=wave_min(ymn); ymx=wave_max(ymx);
  if (l==0){
    red[w][0]=s0; red[w][1]=s1; red[w][2]=s2;
    red[w][3]=q00; red[w][4]=q01; red[w][5]=q02;
    red[w][6]=q11; red[w][7]=q12; red[w][8]=q22;
    red[w][9]=ymn; red[w][10]=ymx;
  }
  __syncthreads();
  if (t<11){
    const float v0=red[0][t],v1=red[1][t],v2=red[2][t],v3=red[3][t];
    float r;
    if (t==9)       r=fminf(fminf(v0,v1),fminf(v2,v3));
    else if (t==10) r=fmaxf(fmaxf(v0,v1),fmaxf(v2,v3));
    else            r=v0+v1+v2+v3;
    ws[OFF_PSTR+bid*16+t]=r;
  }
}

// ---- finA: reduce partials; BN1 fold via quadratic form ----
__global__ void k_finA(const float* __restrict__ w1, const float* __restrict__ b1,
                       const float* __restrict__ gm, const float* __restrict__ bt,
                       float* __restrict__ ws){
  __shared__ float sums[9];
  const int t=threadIdx.x;
  if (t<9){
    float s=0.f;
    #pragma unroll 8
    for (int blk=0;blk<512;blk++) s+=ws[OFF_PSTR+blk*16+t];
    sums[t]=s;
  }
  if (t>=32&&t<48){
    const int b=t-32; float m=3.4e38f;
    #pragma unroll 8
    for (int blk=0;blk<32;blk++) m=fminf(m,ws[OFF_PSTR+(b*32+blk)*16+9]);
    ws[OFF_YMINF+b]=m;
  }
  if (t>=48&&t<64){
    const int b=t-48; float m=-3.4e38f;
    #pragma unroll 8
    for (int blk=0;blk<32;blk++) m=fmaxf(m,ws[OFF_PSTR+(b*32+blk)*16+10]);
    ws[OFF_YMAXF+b]=m;
  }
  __syncthreads();
  if (t<64){
    const float i_n=1.f/NF;
    const float w0=w1[t], wa=w1[64+t], wb=w1[128+t];
    const float ms=(w0*sums[0]+wa*sums[1]+wb*sums[2])*i_n;
    const float es=(w0*w0*sums[3]+wa*wa*sums[6]+wb*wb*sums[8]
                   +2.f*(w0*wa*sums[4]+w0*wb*sums[5]+wa*wb*sums[7]))*i_n;
    const float var=es-ms*ms;
    const float a=gm[t]/sqrtf(var+1e-5f);
    ws[OFF_A1+t]=a; ws[OFF_C1+t]=bt[t]-(ms+b1[t])*a;
  }
}

// ---- bucket segment sums -> per-block partials ----
__global__ __launch_bounds__(256) void k_bucket(const float* __restrict__ x,
                                                float* __restrict__ ws){
  __shared__ float red[4][12];
  const int t=threadIdx.x, l=t&63, w=t>>6;
  const int bid=blockIdx.x, b=bid>>5;
  const float ymn=ws[OFF_YMINF+b], ymx=ws[OFF_YMAXF+b];
  const float4* xv=(const float4*)(x + (size_t)bid*2048*3);
  float sxl[NBK], szl[NBK], cntl[NBK];
  #pragma unroll
  for (int k=0;k<NBK;k++){ sxl[k]=0.f; szl[k]=0.f; cntl[k]=0.f; }
  #pragma unroll
  for (int i=0;i<2;i++){
    const int vi=(i*256+t)*3;
    const float4 a=xv[vi], b4=xv[vi+1], c=xv[vi+2];
    float X[4]={a.x,a.w,b4.z,c.y};
    float Y[4]={a.y,b4.x,b4.w,c.z};
    float Z[4]={a.z,b4.y,c.x,c.w};
    #pragma unroll
    for (int p=0;p<4;p++){
      const float yn=(Y[p]-ymn)/(ymx-ymn+1e-6f);
      int bk=(int)(yn*10.f); bk = bk<0?0:(bk>10?10:bk);
      #pragma unroll
      for (int k=0;k<NBK;k++){
        const bool m=(bk==k);
        sxl[k]+= m?X[p]:0.f; szl[k]+= m?Z[p]:0.f; cntl[k]+= m?1.f:0.f;
      }
    }
  }
  #pragma unroll
  for (int k=0;k<NBK;k++){
    const float s=wave_sum(sxl[k]);
    if (l==0) red[w][k]=s;
  }
  __syncthreads();
  if (t<NBK) ws[OFF_PBKT+bid*36+t]=red[0][t]+red[1][t]+red[2][t]+red[3][t];
  __syncthreads();
  #pragma unroll
  for (int k=0;k<NBK;k++){
    const float z=wave_sum(szl[k]);
    if (l==0) red[w][k]=z;
  }
  __syncthreads();
  if (t<NBK) ws[OFF_PBKT+bid*36+11+t]=red[0][t]+red[1][t]+red[2][t]+red[3][t];
  __syncthreads();
  #pragma unroll
  for (int k=0;k<NBK;k++){
    const float c=wave_sum(cntl[k]);
    if (l==0) red[w][k]=c;
  }
  __syncthreads();
  if (t<NBK) ws[OFF_PBKT+bid*36+22+t]=red[0][t]+red[1][t]+red[2][t]+red[3][t];
}

// ---- finB: reduce h2 partials -> BN2 fold; reduce bucket partials -> centers ----
__global__ void k_finB(const float* __restrict__ gm, const float* __restrict__ bt,
                       float* __restrict__ ws){
  __shared__ float acc[256];
  const int t=threadIdx.x;              // 256 threads
  {
    const int col=t&127, part=t>>7;
    float s=0.f;
    #pragma unroll 8
    for (int blk=0;blk<512;blk++) s+=ws[OFF_PH2+blk*256+part*128+col];
    acc[t]=s;
  }
  __syncthreads();
  if (t<128){
    const float i_n=1.f/NF;
    const float m=acc[t]*i_n;
    const float v=acc[128+t]*i_n-m*m;
    const float a=gm[t]/sqrtf(v+1e-5f);
    ws[OFF_A2+t]=a; ws[OFF_C2+t]=bt[t]-m*a;
  }
  if (t<176){
    const int b=t/NBK, k=t-b*NBK;
    float sx=0.f, sz=0.f, cn=0.f;
    #pragma unroll 8
    for (int blk=0;blk<32;blk++){
      const int p=OFF_PBKT+(b*32+blk)*36;
      sx+=ws[p+k]; sz+=ws[p+11+k]; cn+=ws[p+22+k];
    }
    const float d=fmaxf(cn,1.f);
    ws[OFF_CX+t]=sx/d; ws[OFF_CZ+t]=sz/d;
  }
}

// ---- finC: reduce h3 partials -> BN3 fold ----
__global__ void k_finC(const float* __restrict__ gm, const float* __restrict__ bt,
                       float* __restrict__ ws){
  __shared__ float acc[512];
  const int t=threadIdx.x;              // 512 threads
  {
    const int col=t&255, part=t>>8;
    float s=0.f;
    #pragma unroll 8
    for (int blk=0;blk<512;blk++) s+=ws[OFF_PH3+blk*512+part*256+col];
    acc[t]=s;
  }
  __syncthreads();
  if (t<256){
    const float i_n=1.f/NF;
    const float m=acc[t]*i_n;
    const float v=acc[256+t]*i_n-m*m;
    const float a=gm[t]/sqrtf(v+1e-5f);
    ws[OFF_A3+t]=a; ws[OFF_C3+t]=bt[t]-m*a;
  }
}

// ---- spatial features -> per-block partials ----
__global__ __launch_bounds__(256) void k_spatial(const float* __restrict__ x,
                                                 float* __restrict__ ws){
  __shared__ float red[4][8];
  const int t=threadIdx.x, l=t&63, w=t>>6;
  const int bid=blockIdx.x, b=bid>>5;
  const float ymn=ws[OFF_YMINF+b], ymx=ws[OFF_YMAXF+b];
  const float4* xv=(const float4*)(x + (size_t)bid*2048*3);
  float mx[3]={-3.4e38f,-3.4e38f,-3.4e38f}, sm[3]={0.f,0.f,0.f};
  #pragma unroll
  for (int i=0;i<2;i++){
    const int vi=(i*256+t)*3;
    const float4 a=xv[vi], b4=xv[vi+1], c=xv[vi+2];
    float X[4]={a.x,a.w,b4.z,c.y};
    float Y[4]={a.y,b4.x,b4.w,c.z};
    float Z[4]={a.z,b4.y,c.x,c.w};
    #pragma unroll
    for (int p=0;p<4;p++){
      const float yn=(Y[p]-ymn)/(ymx-ymn+1e-6f);
      int bk=(int)(yn*10.f); bk = bk<0?0:(bk>10?10:bk);
      const float dx=X[p]-ws[OFF_CX+b*NBK+bk];
      const float dz=Z[p]-ws[OFF_CZ+b*NBK+bk];
      const float r=sqrtf(fmaf(dx,dx,dz*dz));
      const float sn=(r>0.f)?(dz/r):0.f;
      const float cs=(r>0.f)?(dx/r):1.f;
      mx[0]=fmaxf(mx[0],sn); sm[0]+=sn;
      mx[1]=fmaxf(mx[1],cs); sm[1]+=cs;
      mx[2]=fmaxf(mx[2],r);  sm[2]+=r;
    }
  }
  #pragma unroll
  for (int q=0;q<3;q++){
    const float m=wave_max(mx[q]);
    const float s=wave_sum(sm[q]);
    if (l==0){ red[w][q]=m; red[w][4+q]=s; }
  }
  __syncthreads();
  if (t<3)        ws[OFF_PSPA+bid*8+t]  =fmaxf(fmaxf(red[0][t],red[1][t]),fmaxf(red[2][t],red[3][t]));
  else if (t>=4&&t<7){
    const int q=t-4;
    ws[OFF_PSPA+bid*8+4+q]=red[0][4+q]+red[1][4+q]+red[2][4+q]+red[3][4+q];
  }
}

// ---- MFMA MLP pass (8 waves, swapped operands) ----
// MODE 0 = h2 stats, 1 = h3 stats, 2 = g3 pooling
template<int MODE>
__global__ __launch_bounds__(512,4) void k_mlp(
    const float* __restrict__ x,
    const float* __restrict__ w1, const float* __restrict__ b1,
    const float* __restrict__ w2, const float* __restrict__ b2,
    const float* __restrict__ w3, const float* __restrict__ b3,
    float* __restrict__ ws)
{
  __shared__ short g1t[64*64];    // [point][feat64] bf16, XOR-swizzled
  __shared__ short g2t[64*128];   // [point][feat128] bf16, XOR-swizzled
  const int t=threadIdx.x, w=t>>6, l=t&63, lg=l>>4, lr=l&15;
  const int bid=blockIdx.x, b=bid>>5, chunk=bid&31;

  // ---- layer1 folded weights: lane handles point p1=8w+(l&7), feats 8fg..8fg+7
  const int p1=8*w+(l&7), fg=l>>3&7;
  const float* a1=ws+OFF_A1; const float* c1=ws+OFF_C1;
  float w1f[3][8], b1f[8];
  #pragma unroll
  for (int i=0;i<8;i++){
    const int f=8*fg+i;
    const float a=a1[f];
    #pragma unroll
    for (int q=0;q<3;q++) w1f[q][i]=w1[q*64+f]*a;
    b1f[i]=b1[f]*a+c1[f];
  }

  // ---- layer2 A-frag (W2^T): wave owns ftile w (feat2 16w..16w+15)
  s16x8 w2f[2]; float b2v[4];
  {
    const int col2=16*w+lr;
    const float sc2=(MODE==0)?1.f:ws[OFF_A2+col2];
    #pragma unroll
    for (int kt=0;kt<2;kt++)
      #pragma unroll
      for (int i=0;i<8;i++)
        w2f[kt][i]=(short)bf16_bits(w2[(kt*32+8*lg+i)*128+col2]*sc2);
    #pragma unroll
    for (int r=0;r<4;r++){
      const int f2=16*w+4*lg+r;
      b2v[r]=(MODE==0)? b2[f2] : (ws[OFF_A2+f2]*b2[f2]+ws[OFF_C2+f2]);
    }
  }

  // ---- layer3 A-frag (W3^T): wave owns ftiles 2w,2w+1 (feat3 32w..32w+31)
  s16x8 w3f[2][4]; float b3v[2][4];
  if (MODE!=0){
    #pragma unroll
    for (int ft=0;ft<2;ft++){
      const int col3=(2*w+ft)*16+lr;
      const float sc3=(MODE==1)?1.f:ws[OFF_A3+col3];
      #pragma unroll
      for (int kt=0;kt<4;kt++)
        #pragma unroll
        for (int i=0;i<8;i++)
          w3f[ft][kt][i]=(short)bf16_bits(w3[(kt*32+8*lg+i)*256+col3]*sc3);
      #pragma unroll
      for (int r=0;r<4;r++){
        const int f3=(2*w+ft)*16+4*lg+r;
        b3v[ft][r]=(MODE==1)? b3[f3] : (ws[OFF_A3+f3]*b3[f3]+ws[OFF_C3+f3]);
      }
    }
  }

  float aS[2][4], aQ[2][4];
  #pragma unroll
  for (int ft=0;ft<2;ft++)
    #pragma unroll
    for (int r=0;r<4;r++){ aS[ft][r]=(MODE==2)?-3.4e38f:0.f; aQ[ft][r]=0.f; }

  char* g1c=(char*)g1t; char* g2c=(char*)g2t;
  const int base=b*N_+chunk*2048;

  #pragma unroll 1
  for (int it=0; it<32; ++it){
    const int tb=base+it*64;
    // ---- layer1: 8 feats for point p1 -> g1 LDS (one b128)
    {
      const float x0=x[(tb+p1)*3+0], x1v=x[(tb+p1)*3+1], x2=x[(tb+p1)*3+2];
      unsigned pk[4];
      #pragma unroll
      for (int i=0;i<4;i++){
        float v0=b1f[2*i],v1=b1f[2*i+1];
        v0=fmaf(x0,w1f[0][2*i],v0);   v1=fmaf(x0,w1f[0][2*i+1],v1);
        v0=fmaf(x1v,w1f[1][2*i],v0);  v1=fmaf(x1v,w1f[1][2*i+1],v1);
        v0=fmaf(x2,w1f[2][2*i],v0);   v1=fmaf(x2,w1f[2][2*i+1],v1);
        v0=fmaxf(v0,0.f); v1=fmaxf(v1,0.f);
        pk[i]=(unsigned)bf16_bits(v0)|((unsigned)bf16_bits(v1)<<16);
      }
      *(int4*)(g1c + ((p1*128+fg*16) ^ ((p1&7)<<4))) = make_int4(pk[0],pk[1],pk[2],pk[3]);
    }
    __syncthreads();
    // ---- layer2: D = W2^T(16) x g1^T(pts); lane holds 4 consecutive feat2 for point lr
    #pragma unroll
    for (int pt=0;pt<4;pt++){
      const int p=pt*16+lr;
      s16x8 bf[2];
      #pragma unroll
      for (int kt=0;kt<2;kt++)
        bf[kt]=*(const s16x8*)(g1c + ((p*128+kt*64+16*lg) ^ ((p&7)<<4)));
      f32x4 acc={0.f,0.f,0.f,0.f};
      acc=__builtin_amdgcn_mfma_f32_16x16x32_bf16(w2f[0],bf[0],acc,0,0,0);
      acc=__builtin_amdgcn_mfma_f32_16x16x32_bf16(w2f[1],bf[1],acc,0,0,0);
      if (MODE==0){
        #pragma unroll
        for (int r=0;r<4;r++){
          const float h=acc[r]+b2v[r];
          aS[0][r]+=h; aQ[0][r]+=h*h;
        }
      } else {
        float g0=fmaxf(acc[0]+b2v[0],0.f), g1v=fmaxf(acc[1]+b2v[1],0.f);
        float g2v=fmaxf(acc[2]+b2v[2],0.f), g3=fmaxf(acc[3]+b2v[3],0.f);
        const unsigned lo=(unsigned)bf16_bits(g0)|((unsigned)bf16_bits(g1v)<<16);
        const unsigned hi=(unsigned)bf16_bits(g2v)|((unsigned)bf16_bits(g3)<<16);
        *(uint2*)(g2c + ((p*256+w*32+lg*8) ^ ((p&7)<<4))) = make_uint2(lo,hi);
      }
    }
    __syncthreads();
    // ---- layer3: D = W3^T(32) x g2^T(pts)
    if (MODE!=0){
      #pragma unroll
      for (int pt=0;pt<4;pt++){
        const int p=pt*16+lr;
        s16x8 bf[4];
        #pragma unroll
        for (int kt=0;kt<4;kt++)
          bf[kt]=*(const s16x8*)(g2c + ((p*256+kt*64+16*lg) ^ ((p&7)<<4)));
        #pragma unroll
        for (int ft=0;ft<2;ft++){
          f32x4 acc={0.f,0.f,0.f,0.f};
          #pragma unroll
          for (int kt=0;kt<4;kt++)
            acc=__builtin_amdgcn_mfma_f32_16x16x32_bf16(w3f[ft][kt],bf[kt],acc,0,0,0);
          #pragma unroll
          for (int r=0;r<4;r++){
            if (MODE==1){
              const float h=acc[r]+b3v[ft][r];
              aS[ft][r]+=h; aQ[ft][r]+=h*h;
            } else {
              const float g=fmaxf(acc[r]+b3v[ft][r],0.f);
              aS[ft][r]=fmaxf(aS[ft][r],g); aQ[ft][r]+=g;
            }
          }
        }
      }
    }
  }

  // ---- flush: reduce over lr (16-lane groups), lane lr==0 writes partials
  if (MODE==0){
    #pragma unroll
    for (int r=0;r<4;r++){
      float s=aS[0][r], q=aQ[0][r];
      #pragma unroll
      for (int m=1;m<16;m<<=1){ s+=__shfl_xor(s,m); q+=__shfl_xor(q,m); }
      if (lr==0){
        const int f2=16*w+4*lg+r;
        ws[OFF_PH2+bid*256+f2]    =s;
        ws[OFF_PH2+bid*256+128+f2]=q;
      }
    }
  } else if (MODE==1){
    #pragma unroll
    for (int ft=0;ft<2;ft++)
      #pragma unroll
      for (int r=0;r<4;r++){
        float s=aS[ft][r], q=aQ[ft][r];
        #pragma unroll
        for (int m=1;m<16;m<<=1){ s+=__shfl_xor(s,m); q+=__shfl_xor(q,m); }
        if (lr==0){
          const int f3=(2*w+ft)*16+4*lg+r;
          ws[OFF_PH3+bid*512+f3]    =s;
          ws[OFF_PH3+bid*512+256+f3]=q;
        }
      }
  } else {
    #pragma unroll
    for (int ft=0;ft<2;ft++)
      #pragma unroll
      for (int r=0;r<4;r++){
        float mxv=aS[ft][r], s=aQ[ft][r];
        #pragma unroll
        for (int m=1;m<16;m<<=1){ mxv=fmaxf(mxv,__shfl_xor(mxv,m)); s+=__shfl_xor(s,m); }
        if (lr==0){
          const int f3=(2*w+ft)*16+4*lg+r;
          ws[OFF_PPOOL+bid*512+f3]    =mxv;
          ws[OFF_PPOOL+bid*512+256+f3]=s;
        }
      }
  }
}

// ---- final: reduce pool partials, feat_cat(518) @ wp + bp, LayerNorm ----
__global__ __launch_bounds__(256) void k_final(
    const float* __restrict__ wp, const float* __restrict__ bp,
    const float* __restrict__ gln, const float* __restrict__ bln,
    float* __restrict__ out, const float* __restrict__ ws)
{
  __shared__ float feat[518];
  __shared__ float red[256];
  const int b=blockIdx.x, t=threadIdx.x;
  {
    float fm=-3.4e38f, fs=0.f;
    #pragma unroll 4
    for (int blk=0;blk<32;blk++){
      const int p=OFF_PPOOL+(b*32+blk)*512;
      fm=fmaxf(fm,ws[p+t]);
      fs+=ws[p+256+t];
    }
    feat[t]=fm; feat[NFEAT+t]=fs*(1.f/65536.f);
  }
  if (t<3){
    float fm=-3.4e38f, fs=0.f;
    #pragma unroll 4
    for (int blk=0;blk<32;blk++){
      const int p=OFF_PSPA+(b*32+blk)*8;
      fm=fmaxf(fm,ws[p+t]);
      fs+=ws[p+4+t];
    }
    feat[256+t]=fm; feat[NFEAT+256+t]=fs*(1.f/65536.f);
  }
  __syncthreads();
  float o0=bp[t], o1=bp[t+256];
  #pragma unroll 4
  for (int i=0;i<518;i++){
    const float f=feat[i];
    o0=fmaf(f, wp[i*512+t],     o0);
    o1=fmaf(f, wp[i*512+t+256], o1);
  }
  red[t]=o0+o1; __syncthreads();
  for (int s=128;s>0;s>>=1){ if (t<s) red[t]+=red[t+s]; __syncthreads(); }
  const float mu=red[0]*(1.f/512.f);
  __syncthreads();
  const float d0=o0-mu, d1=o1-mu;
  red[t]=d0*d0+d1*d1; __syncthreads();
  for (int s=128;s>0;s>>=1){ if (t<s) red[t]+=red[t+s]; __syncthreads(); }
  const float var=red[0]*(1.f/512.f);
  const float rs=1.f/sqrtf(var+1e-5f);
  out[b*512+t]     = d0*rs*gln[t]    +bln[t];
  out[b*512+t+256] = d1*rs*gln[t+256]+bln[t+256];
}

extern "C" void kernel_launch(void* const* d_in, const int* in_sizes, int n_in,
                              void* d_out, int out_size, void* d_ws, size_t ws_size,
                              hipStream_t stream)
{
  const float* x  =(const float*)d_in[0];
  const float* w1 =(const float*)d_in[1];
  const float* b1 =(const float*)d_in[2];
  const float* gm1=(const float*)d_in[3];
  const float* be1=(const float*)d_in[4];
  const float* w2 =(const float*)d_in[5];
  const float* b2 =(const float*)d_in[6];
  const float* gm2=(const float*)d_in[7];
  const float* be2=(const float*)d_in[8];
  const float* w3 =(const float*)d_in[9];
  const float* b3 =(const float*)d_in[10];
  const float* gm3=(const float*)d_in[11];
  const float* be3=(const float*)d_in[12];
  const float* wp =(const float*)d_in[13];
  const float* bp =(const float*)d_in[14];
  const float* gln=(const float*)d_in[15];
  const float* bln=(const float*)d_in[16];
  float* ws=(float*)d_ws;
  float* out=(float*)d_out;

  k_stream0<<<dim3(512),dim3(256),0,stream>>>(x,ws);
  k_finA   <<<dim3(1),  dim3(256),0,stream>>>(w1,b1,gm1,be1,ws);
  k_bucket <<<dim3(512),dim3(256),0,stream>>>(x,ws);
  k_mlp<0> <<<dim3(512),dim3(512),0,stream>>>(x,w1,b1,w2,b2,w3,b3,ws);
  k_finB   <<<dim3(1),  dim3(256),0,stream>>>(gm2,be2,ws);
  k_spatial<<<dim3(512),dim3(256),0,stream>>>(x,ws);
  k_mlp<1> <<<dim3(512),dim3(512),0,stream>>>(x,w1,b1,w2,b2,w3,b3,ws);
  k_finC   <<<dim3(1),  dim3(512),0,stream>>>(gm3,be3,ws);
  k_mlp<2> <<<dim3(512),dim3(512),0,stream>>>(x,w1,b1,w2,b2,w3,b3,ws);
  k_final  <<<dim3(16), dim3(256),0,stream>>>(wp,bp,gln,bln,out,ws);
}

// Round 5
// 440.072 us; speedup vs baseline: 2.1932x; 2.1932x over previous
//
#include <hip/hip_runtime.h>
#include <stdint.h>

#define B_    16
#define N_    65536
#define NPTS  (B_*N_)
#define NBK   11
#define NFEAT 259
#define NF    ((float)NPTS)

typedef float f32x4 __attribute__((ext_vector_type(4)));
typedef short s16x8 __attribute__((ext_vector_type(8)));

// ---- workspace float offsets ----
enum {
  OFF_YMINF = 16,     // 16
  OFF_YMAXF = 32,     // 16
  OFF_A1    = 64,     // 64
  OFF_C1    = 128,    // 64
  OFF_A2    = 192,    // 128
  OFF_C2    = 320,    // 128
  OFF_CX    = 448,    // 176
  OFF_CZ    = 624,    // 176
  OFF_A3    = 800,    // 256
  OFF_C3    = 1056,   // 256
  // per-block partials (512 blocks)
  OFF_PSTR  = 16384,  // 512*16 : s0,s1,s2,q00,q01,q02,q11,q12,q22,ymn,ymx
  OFF_PBKT  = 24576,  // 512*36 : sx[11], sz[11], cnt[11]
  OFF_PH2   = 49152,  // 512*256: sum[128], sq[128]
  OFF_PH3   = 180224, // 512*512: sum[256], sq[256]
  OFF_PPOOL = 442368, // 512*512: max[256], sum[256]
  OFF_PSPA  = 704512  // 512*8  : max[3], sum[3]
};

// ---- helpers ----
__device__ __forceinline__ float wave_sum(float v){
  #pragma unroll
  for (int m=32;m>=1;m>>=1) v += __shfl_xor(v,m,64);
  return v;
}
__device__ __forceinline__ float wave_max(float v){
  #pragma unroll
  for (int m=32;m>=1;m>>=1) v = fmaxf(v,__shfl_xor(v,m,64));
  return v;
}
__device__ __forceinline__ float wave_min(float v){
  #pragma unroll
  for (int m=32;m>=1;m>>=1) v = fminf(v,__shfl_xor(v,m,64));
  return v;
}
__device__ __forceinline__ unsigned short bf16_bits(float f){
  unsigned u=__float_as_uint(f);
  u += 0x7FFFu + ((u>>16)&1u);
  return (unsigned short)(u>>16);
}

// ---- pass A: x colsums + X^T X + per-batch y min/max -> per-block partials ----
__global__ __launch_bounds__(256) void k_stream0(const float* __restrict__ x,
                                                 float* __restrict__ ws){
  __shared__ float red[4][12];
  const int t=threadIdx.x, l=t&63, w=t>>6;
  const int bid=blockIdx.x;
  const float4* xv=(const float4*)(x + (size_t)bid*2048*3);
  float s0=0,s1=0,s2=0,q00=0,q01=0,q02=0,q11=0,q12=0,q22=0;
  float ymn=3.4e38f, ymx=-3.4e38f;
  #pragma unroll
  for (int i=0;i<2;i++){
    const int vi=(i*256+t)*3;
    const float4 a=xv[vi], b4=xv[vi+1], c=xv[vi+2];
    float X[4]={a.x,a.w,b4.z,c.y};
    float Y[4]={a.y,b4.x,b4.w,c.z};
    float Z[4]={a.z,b4.y,c.x,c.w};
    #pragma unroll
    for (int p=0;p<4;p++){
      s0+=X[p]; s1+=Y[p]; s2+=Z[p];
      q00=fmaf(X[p],X[p],q00); q01=fmaf(X[p],Y[p],q01); q02=fmaf(X[p],Z[p],q02);
      q11=fmaf(Y[p],Y[p],q11); q12=fmaf(Y[p],Z[p],q12); q22=fmaf(Z[p],Z[p],q22);
      ymn=fminf(ymn,Y[p]); ymx=fmaxf(ymx,Y[p]);
    }
  }
  s0=wave_sum(s0); s1=wave_sum(s1); s2=wave_sum(s2);
  q00=wave_sum(q00); q01=wave_sum(q01); q02=wave_sum(q02);
  q11=wave_sum(q11); q12=wave_sum(q12); q22=wave_sum(q22);
  ymn=wave_min(ymn); ymx=wave_max(ymx);
  if (l==0){
    red[w][0]=s0; red[w][1]=s1; red[w][2]=s2;
    red[w][3]=q00; red[w][4]=q01; red[w][5]=q02;
    red[w][6]=q11; red[w][7]=q12; red[w][8]=q22;
    red[w][9]=ymn; red[w][10]=ymx;
  }
  __syncthreads();
  if (t<11){
    const float v0=red[0][t],v1=red[1][t],v2=red[2][t],v3=red[3][t];
    float r;
    if (t==9)       r=fminf(fminf(v0,v1),fminf(v2,v3));
    else if (t==10) r=fmaxf(fmaxf(v0,v1),fmaxf(v2,v3));
    else            r=v0+v1+v2+v3;
    ws[OFF_PSTR+bid*16+t]=r;
  }
}

// ---- finA: reduce partials; BN1 fold via quadratic form ----
__global__ void k_finA(const float* __restrict__ w1, const float* __restrict__ b1,
                       const float* __restrict__ gm, const float* __restrict__ bt,
                       float* __restrict__ ws){
  __shared__ float sums[9];
  const int t=threadIdx.x;
  if (t<9){
    float s=0.f;
    #pragma unroll 8
    for (int blk=0;blk<512;blk++) s+=ws[OFF_PSTR+blk*16+t];
    sums[t]=s;
  }
  if (t>=32&&t<48){
    const int b=t-32; float m=3.4e38f;
    #pragma unroll 8
    for (int blk=0;blk<32;blk++) m=fminf(m,ws[OFF_PSTR+(b*32+blk)*16+9]);
    ws[OFF_YMINF+b]=m;
  }
  if (t>=48&&t<64){
    const int b=t-48; float m=-3.4e38f;
    #pragma unroll 8
    for (int blk=0;blk<32;blk++) m=fmaxf(m,ws[OFF_PSTR+(b*32+blk)*16+10]);
    ws[OFF_YMAXF+b]=m;
  }
  __syncthreads();
  if (t<64){
    const float i_n=1.f/NF;
    const float w0=w1[t], wa=w1[64+t], wb=w1[128+t];
    const float ms=(w0*sums[0]+wa*sums[1]+wb*sums[2])*i_n;
    const float es=(w0*w0*sums[3]+wa*wa*sums[6]+wb*wb*sums[8]
                   +2.f*(w0*wa*sums[4]+w0*wb*sums[5]+wa*wb*sums[7]))*i_n;
    const float var=es-ms*ms;
    const float a=gm[t]/sqrtf(var+1e-5f);
    ws[OFF_A1+t]=a; ws[OFF_C1+t]=bt[t]-(ms+b1[t])*a;
  }
}

// ---- bucket segment sums -> per-block partials ----
__global__ __launch_bounds__(256) void k_bucket(const float* __restrict__ x,
                                                float* __restrict__ ws){
  __shared__ float red[4][12];
  const int t=threadIdx.x, l=t&63, w=t>>6;
  const int bid=blockIdx.x, b=bid>>5;
  const float ymn=ws[OFF_YMINF+b], ymx=ws[OFF_YMAXF+b];
  const float4* xv=(const float4*)(x + (size_t)bid*2048*3);
  float sxl[NBK], szl[NBK], cntl[NBK];
  #pragma unroll
  for (int k=0;k<NBK;k++){ sxl[k]=0.f; szl[k]=0.f; cntl[k]=0.f; }
  #pragma unroll
  for (int i=0;i<2;i++){
    const int vi=(i*256+t)*3;
    const float4 a=xv[vi], b4=xv[vi+1], c=xv[vi+2];
    float X[4]={a.x,a.w,b4.z,c.y};
    float Y[4]={a.y,b4.x,b4.w,c.z};
    float Z[4]={a.z,b4.y,c.x,c.w};
    #pragma unroll
    for (int p=0;p<4;p++){
      const float yn=(Y[p]-ymn)/(ymx-ymn+1e-6f);
      int bk=(int)(yn*10.f); bk = bk<0?0:(bk>10?10:bk);
      #pragma unroll
      for (int k=0;k<NBK;k++){
        const bool m=(bk==k);
        sxl[k]+= m?X[p]:0.f; szl[k]+= m?Z[p]:0.f; cntl[k]+= m?1.f:0.f;
      }
    }
  }
  #pragma unroll
  for (int k=0;k<NBK;k++){
    const float s=wave_sum(sxl[k]);
    if (l==0) red[w][k]=s;
  }
  __syncthreads();
  if (t<NBK) ws[OFF_PBKT+bid*36+t]=red[0][t]+red[1][t]+red[2][t]+red[3][t];
  __syncthreads();
  #pragma unroll
  for (int k=0;k<NBK;k++){
    const float z=wave_sum(szl[k]);
    if (l==0) red[w][k]=z;
  }
  __syncthreads();
  if (t<NBK) ws[OFF_PBKT+bid*36+11+t]=red[0][t]+red[1][t]+red[2][t]+red[3][t];
  __syncthreads();
  #pragma unroll
  for (int k=0;k<NBK;k++){
    const float c=wave_sum(cntl[k]);
    if (l==0) red[w][k]=c;
  }
  __syncthreads();
  if (t<NBK) ws[OFF_PBKT+bid*36+22+t]=red[0][t]+red[1][t]+red[2][t]+red[3][t];
}

// ---- finB: reduce h2 partials -> BN2 fold; reduce bucket partials -> centers ----
__global__ void k_finB(const float* __restrict__ gm, const float* __restrict__ bt,
                       float* __restrict__ ws){
  __shared__ float acc[256];
  const int t=threadIdx.x;              // 256 threads
  {
    const int col=t&127, part=t>>7;
    float s=0.f;
    #pragma unroll 8
    for (int blk=0;blk<512;blk++) s+=ws[OFF_PH2+blk*256+part*128+col];
    acc[t]=s;
  }
  __syncthreads();
  if (t<128){
    const float i_n=1.f/NF;
    const float m=acc[t]*i_n;
    const float v=acc[128+t]*i_n-m*m;
    const float a=gm[t]/sqrtf(v+1e-5f);
    ws[OFF_A2+t]=a; ws[OFF_C2+t]=bt[t]-m*a;
  }
  if (t<176){
    const int b=t/NBK, k=t-b*NBK;
    float sx=0.f, sz=0.f, cn=0.f;
    #pragma unroll 8
    for (int blk=0;blk<32;blk++){
      const int p=OFF_PBKT+(b*32+blk)*36;
      sx+=ws[p+k]; sz+=ws[p+11+k]; cn+=ws[p+22+k];
    }
    const float d=fmaxf(cn,1.f);
    ws[OFF_CX+t]=sx/d; ws[OFF_CZ+t]=sz/d;
  }
}

// ---- finC: reduce h3 partials -> BN3 fold ----
__global__ void k_finC(const float* __restrict__ gm, const float* __restrict__ bt,
                       float* __restrict__ ws){
  __shared__ float acc[512];
  const int t=threadIdx.x;              // 512 threads
  {
    const int col=t&255, part=t>>8;
    float s=0.f;
    #pragma unroll 8
    for (int blk=0;blk<512;blk++) s+=ws[OFF_PH3+blk*512+part*256+col];
    acc[t]=s;
  }
  __syncthreads();
  if (t<256){
    const float i_n=1.f/NF;
    const float m=acc[t]*i_n;
    const float v=acc[256+t]*i_n-m*m;
    const float a=gm[t]/sqrtf(v+1e-5f);
    ws[OFF_A3+t]=a; ws[OFF_C3+t]=bt[t]-m*a;
  }
}

// ---- spatial features -> per-block partials ----
__global__ __launch_bounds__(256) void k_spatial(const float* __restrict__ x,
                                                 float* __restrict__ ws){
  __shared__ float red[4][8];
  const int t=threadIdx.x, l=t&63, w=t>>6;
  const int bid=blockIdx.x, b=bid>>5;
  const float ymn=ws[OFF_YMINF+b], ymx=ws[OFF_YMAXF+b];
  const float4* xv=(const float4*)(x + (size_t)bid*2048*3);
  float mx[3]={-3.4e38f,-3.4e38f,-3.4e38f}, sm[3]={0.f,0.f,0.f};
  #pragma unroll
  for (int i=0;i<2;i++){
    const int vi=(i*256+t)*3;
    const float4 a=xv[vi], b4=xv[vi+1], c=xv[vi+2];
    float X[4]={a.x,a.w,b4.z,c.y};
    float Y[4]={a.y,b4.x,b4.w,c.z};
    float Z[4]={a.z,b4.y,c.x,c.w};
    #pragma unroll
    for (int p=0;p<4;p++){
      const float yn=(Y[p]-ymn)/(ymx-ymn+1e-6f);
      int bk=(int)(yn*10.f); bk = bk<0?0:(bk>10?10:bk);
      const float dx=X[p]-ws[OFF_CX+b*NBK+bk];
      const float dz=Z[p]-ws[OFF_CZ+b*NBK+bk];
      const float r=sqrtf(fmaf(dx,dx,dz*dz));
      const float sn=(r>0.f)?(dz/r):0.f;
      const float cs=(r>0.f)?(dx/r):1.f;
      mx[0]=fmaxf(mx[0],sn); sm[0]+=sn;
      mx[1]=fmaxf(mx[1],cs); sm[1]+=cs;
      mx[2]=fmaxf(mx[2],r);  sm[2]+=r;
    }
  }
  #pragma unroll
  for (int q=0;q<3;q++){
    const float m=wave_max(mx[q]);
    const float s=wave_sum(sm[q]);
    if (l==0){ red[w][q]=m; red[w][4+q]=s; }
  }
  __syncthreads();
  if (t<3)        ws[OFF_PSPA+bid*8+t]  =fmaxf(fmaxf(red[0][t],red[1][t]),fmaxf(red[2][t],red[3][t]));
  else if (t>=4&&t<7){
    const int q=t-4;
    ws[OFF_PSPA+bid*8+4+q]=red[0][4+q]+red[1][4+q]+red[2][4+q]+red[3][4+q];
  }
}

// ---- MFMA MLP pass (8 waves, swapped operands, padded LDS, 128-pt tiles) ----
// MODE 0 = h2 stats, 1 = h3 stats, 2 = g3 pooling
// LDS: g1 [128][72] shorts (144B rows), g2 [128][136] shorts (272B rows) -> conflict-free
template<int MODE>
__global__ __launch_bounds__(512,2) void k_mlp(
    const float* __restrict__ x,
    const float* __restrict__ w1, const float* __restrict__ b1,
    const float* __restrict__ w2, const float* __restrict__ b2,
    const float* __restrict__ w3, const float* __restrict__ b3,
    float* __restrict__ ws)
{
  __shared__ short g1t[128*72];
  __shared__ short g2t[128*136];
  const int t=threadIdx.x, w=t>>6, l=t&63, lg=l>>4, lr=l&15;
  const int bid=blockIdx.x, b=bid>>5, chunk=bid&31;
  char* g1c=(char*)g1t; char* g2c=(char*)g2t;

  // ---- layer1 folded weights: lane computes feats 8fg..8fg+7 for 2 pts
  const int fg=l&7, pj=(l>>3)&7;
  const float* a1=ws+OFF_A1; const float* c1=ws+OFF_C1;
  float w1f[3][8], b1f[8];
  #pragma unroll
  for (int i=0;i<8;i++){
    const int f=8*fg+i; const float a=a1[f];
    #pragma unroll
    for (int q=0;q<3;q++) w1f[q][i]=w1[q*64+f]*a;
    b1f[i]=b1[f]*a+c1[f];
  }

  // ---- layer2 A-frag (W2^T): wave owns f2-tile w (16 feats)
  s16x8 w2f[2]; float b2v[4];
  {
    const int col2=16*w+lr;
    const float sc2=(MODE==0)?1.f:ws[OFF_A2+col2];
    #pragma unroll
    for (int kt=0;kt<2;kt++)
      #pragma unroll
      for (int i=0;i<8;i++)
        w2f[kt][i]=(short)bf16_bits(w2[(kt*32+8*lg+i)*128+col2]*sc2);
    #pragma unroll
    for (int r=0;r<4;r++){
      const int f2=16*w+4*lg+r;
      b2v[r]=(MODE==0)? b2[f2] : (ws[OFF_A2+f2]*b2[f2]+ws[OFF_C2+f2]);
    }
  }

  // ---- layer3 A-frags (W3^T): wave owns f3-tiles 2w, 2w+1 (32 feats)
  s16x8 w3f[2][4]; float b3v[2][4];
  if (MODE!=0){
    #pragma unroll
    for (int ft=0;ft<2;ft++){
      const int col3=(2*w+ft)*16+lr;
      const float sc3=(MODE==1)?1.f:ws[OFF_A3+col3];
      #pragma unroll
      for (int kt=0;kt<4;kt++)
        #pragma unroll
        for (int i=0;i<8;i++)
          w3f[ft][kt][i]=(short)bf16_bits(w3[(kt*32+8*lg+i)*256+col3]*sc3);
      #pragma unroll
      for (int r=0;r<4;r++){
        const int f3=(2*w+ft)*16+4*lg+r;
        b3v[ft][r]=(MODE==1)? b3[f3] : (ws[OFF_A3+f3]*b3[f3]+ws[OFF_C3+f3]);
      }
    }
  }

  float aS[2][4], aQ[2][4];
  #pragma unroll
  for (int ft=0;ft<2;ft++)
    #pragma unroll
    for (int r=0;r<4;r++){ aS[ft][r]=(MODE==2)?-3.4e38f:0.f; aQ[ft][r]=0.f; }

  const int base=b*N_+chunk*2048;

  #pragma unroll 1
  for (int it=0; it<16; ++it){
    const int tb=base+it*128;
    // ---- layer1: 8 feats x 2 pts per lane -> g1 (b128 each)
    #pragma unroll
    for (int s=0;s<2;s++){
      const int pt=16*w+2*pj+s;
      const float x0=x[(tb+pt)*3+0], x1v=x[(tb+pt)*3+1], x2=x[(tb+pt)*3+2];
      unsigned pk[4];
      #pragma unroll
      for (int i=0;i<4;i++){
        float v0=b1f[2*i], v1=b1f[2*i+1];
        v0=fmaf(x0,w1f[0][2*i],v0);  v1=fmaf(x0,w1f[0][2*i+1],v1);
        v0=fmaf(x1v,w1f[1][2*i],v0); v1=fmaf(x1v,w1f[1][2*i+1],v1);
        v0=fmaf(x2,w1f[2][2*i],v0);  v1=fmaf(x2,w1f[2][2*i+1],v1);
        pk[i]=(unsigned)bf16_bits(fmaxf(v0,0.f))|((unsigned)bf16_bits(fmaxf(v1,0.f))<<16);
      }
      *(int4*)(g1c + pt*144 + fg*16) = make_int4(pk[0],pk[1],pk[2],pk[3]);
    }
    __syncthreads();
    // ---- layer2: D = W2^T x g1^T ; lane gets 4 consecutive f2 for pt row
    #pragma unroll 2
    for (int ptile=0;ptile<8;ptile++){
      const int row=ptile*16+lr;
      const s16x8 bf0=*(const s16x8*)(g1c + row*144 + lg*16);
      const s16x8 bf1=*(const s16x8*)(g1c + row*144 + 64 + lg*16);
      f32x4 acc={0.f,0.f,0.f,0.f};
      acc=__builtin_amdgcn_mfma_f32_16x16x32_bf16(w2f[0],bf0,acc,0,0,0);
      acc=__builtin_amdgcn_mfma_f32_16x16x32_bf16(w2f[1],bf1,acc,0,0,0);
      if (MODE==0){
        #pragma unroll
        for (int r=0;r<4;r++){ const float h=acc[r]+b2v[r]; aS[0][r]+=h; aQ[0][r]+=h*h; }
      } else {
        const float g0=fmaxf(acc[0]+b2v[0],0.f), g1v=fmaxf(acc[1]+b2v[1],0.f);
        const float g2v=fmaxf(acc[2]+b2v[2],0.f), g3v=fmaxf(acc[3]+b2v[3],0.f);
        const unsigned lo=(unsigned)bf16_bits(g0)|((unsigned)bf16_bits(g1v)<<16);
        const unsigned hi=(unsigned)bf16_bits(g2v)|((unsigned)bf16_bits(g3v)<<16);
        *(uint2*)(g2c + row*272 + w*32 + lg*8) = make_uint2(lo,hi);
      }
    }
    __syncthreads();
    // ---- layer3: D = W3^T x g2^T (only 2 B-frags live at a time)
    if (MODE!=0){
      #pragma unroll 1
      for (int ptile=0;ptile<8;ptile++){
        const int row=ptile*16+lr;
        s16x8 bf0=*(const s16x8*)(g2c + row*272 + lg*16);
        s16x8 bf1=*(const s16x8*)(g2c + row*272 + 64 + lg*16);
        f32x4 a0={0.f,0.f,0.f,0.f}, a1v={0.f,0.f,0.f,0.f};
        a0 =__builtin_amdgcn_mfma_f32_16x16x32_bf16(w3f[0][0],bf0,a0 ,0,0,0);
        a1v=__builtin_amdgcn_mfma_f32_16x16x32_bf16(w3f[1][0],bf0,a1v,0,0,0);
        a0 =__builtin_amdgcn_mfma_f32_16x16x32_bf16(w3f[0][1],bf1,a0 ,0,0,0);
        a1v=__builtin_amdgcn_mfma_f32_16x16x32_bf16(w3f[1][1],bf1,a1v,0,0,0);
        bf0=*(const s16x8*)(g2c + row*272 + 128 + lg*16);
        bf1=*(const s16x8*)(g2c + row*272 + 192 + lg*16);
        a0 =__builtin_amdgcn_mfma_f32_16x16x32_bf16(w3f[0][2],bf0,a0 ,0,0,0);
        a1v=__builtin_amdgcn_mfma_f32_16x16x32_bf16(w3f[1][2],bf0,a1v,0,0,0);
        a0 =__builtin_amdgcn_mfma_f32_16x16x32_bf16(w3f[0][3],bf1,a0 ,0,0,0);
        a1v=__builtin_amdgcn_mfma_f32_16x16x32_bf16(w3f[1][3],bf1,a1v,0,0,0);
        #pragma unroll
        for (int r=0;r<4;r++){
          if (MODE==1){
            const float h0=a0[r] +b3v[0][r]; aS[0][r]+=h0; aQ[0][r]+=h0*h0;
            const float h1=a1v[r]+b3v[1][r]; aS[1][r]+=h1; aQ[1][r]+=h1*h1;
          } else {
            const float g0=fmaxf(a0[r] +b3v[0][r],0.f);
            const float g1v=fmaxf(a1v[r]+b3v[1][r],0.f);
            aS[0][r]=fmaxf(aS[0][r],g0); aQ[0][r]+=g0;
            aS[1][r]=fmaxf(aS[1][r],g1v); aQ[1][r]+=g1v;
          }
        }
      }
    }
  }

  // ---- flush: reduce over lr (16-lane groups), lane lr==0 writes partials
  if (MODE==0){
    #pragma unroll
    for (int r=0;r<4;r++){
      float s=aS[0][r], q=aQ[0][r];
      #pragma unroll
      for (int m=1;m<16;m<<=1){ s+=__shfl_xor(s,m); q+=__shfl_xor(q,m); }
      if (lr==0){
        const int f2=16*w+4*lg+r;
        ws[OFF_PH2+bid*256+f2]    =s;
        ws[OFF_PH2+bid*256+128+f2]=q;
      }
    }
  } else if (MODE==1){
    #pragma unroll
    for (int ft=0;ft<2;ft++)
      #pragma unroll
      for (int r=0;r<4;r++){
        float s=aS[ft][r], q=aQ[ft][r];
        #pragma unroll
        for (int m=1;m<16;m<<=1){ s+=__shfl_xor(s,m); q+=__shfl_xor(q,m); }
        if (lr==0){
          const int f3=(2*w+ft)*16+4*lg+r;
          ws[OFF_PH3+bid*512+f3]    =s;
          ws[OFF_PH3+bid*512+256+f3]=q;
        }
      }
  } else {
    #pragma unroll
    for (int ft=0;ft<2;ft++)
      #pragma unroll
      for (int r=0;r<4;r++){
        float mxv=aS[ft][r], s=aQ[ft][r];
        #pragma unroll
        for (int m=1;m<16;m<<=1){ mxv=fmaxf(mxv,__shfl_xor(mxv,m)); s+=__shfl_xor(s,m); }
        if (lr==0){
          const int f3=(2*w+ft)*16+4*lg+r;
          ws[OFF_PPOOL+bid*512+f3]    =mxv;
          ws[OFF_PPOOL+bid*512+256+f3]=s;
        }
      }
  }
}

// ---- final: reduce pool partials, feat_cat(518) @ wp + bp, LayerNorm ----
__global__ __launch_bounds__(256) void k_final(
    const float* __restrict__ wp, const float* __restrict__ bp,
    const float* __restrict__ gln, const float* __restrict__ bln,
    float* __restrict__ out, const float* __restrict__ ws)
{
  __shared__ float feat[518];
  __shared__ float red[256];
  const int b=blockIdx.x, t=threadIdx.x;
  {
    float fm=-3.4e38f, fs=0.f;
    #pragma unroll 4
    for (int blk=0;blk<32;blk++){
      const int p=OFF_PPOOL+(b*32+blk)*512;
      fm=fmaxf(fm,ws[p+t]);
      fs+=ws[p+256+t];
    }
    feat[t]=fm; feat[NFEAT+t]=fs*(1.f/65536.f);
  }
  if (t<3){
    float fm=-3.4e38f, fs=0.f;
    #pragma unroll 4
    for (int blk=0;blk<32;blk++){
      const int p=OFF_PSPA+(b*32+blk)*8;
      fm=fmaxf(fm,ws[p+t]);
      fs+=ws[p+4+t];
    }
    feat[256+t]=fm; feat[NFEAT+256+t]=fs*(1.f/65536.f);
  }
  __syncthreads();
  float o0=bp[t], o1=bp[t+256];
  #pragma unroll 4
  for (int i=0;i<518;i++){
    const float f=feat[i];
    o0=fmaf(f, wp[i*512+t],     o0);
    o1=fmaf(f, wp[i*512+t+256], o1);
  }
  red[t]=o0+o1; __syncthreads();
  for (int s=128;s>0;s>>=1){ if (t<s) red[t]+=red[t+s]; __syncthreads(); }
  const float mu=red[0]*(1.f/512.f);
  __syncthreads();
  const float d0=o0-mu, d1=o1-mu;
  red[t]=d0*d0+d1*d1; __syncthreads();
  for (int s=128;s>0;s>>=1){ if (t<s) red[t]+=red[t+s]; __syncthreads(); }
  const float var=red[0]*(1.f/512.f);
  const float rs=1.f/sqrtf(var+1e-5f);
  out[b*512+t]     = d0*rs*gln[t]    +bln[t];
  out[b*512+t+256] = d1*rs*gln[t+256]+bln[t+256];
}

extern "C" void kernel_launch(void* const* d_in, const int* in_sizes, int n_in,
                              void* d_out, int out_size, void* d_ws, size_t ws_size,
                              hipStream_t stream)
{
  const float* x  =(const float*)d_in[0];
  const float* w1 =(const float*)d_in[1];
  const float* b1 =(const float*)d_in[2];
  const float* gm1=(const float*)d_in[3];
  const float* be1=(const float*)d_in[4];
  const float* w2 =(const float*)d_in[5];
  const float* b2 =(const float*)d_in[6];
  const float* gm2=(const float*)d_in[7];
  const float* be2=(const float*)d_in[8];
  const float* w3 =(const float*)d_in[9];
  const float* b3 =(const float*)d_in[10];
  const float* gm3=(const float*)d_in[11];
  const float* be3=(const float*)d_in[12];
  const float* wp =(const float*)d_in[13];
  const float* bp =(const float*)d_in[14];
  const float* gln=(const float*)d_in[15];
  const float* bln=(const float*)d_in[16];
  float* ws=(float*)d_ws;
  float* out=(float*)d_out;

  k_stream0<<<dim3(512),dim3(256),0,stream>>>(x,ws);
  k_finA   <<<dim3(1),  dim3(256),0,stream>>>(w1,b1,gm1,be1,ws);
  k_bucket <<<dim3(512),dim3(256),0,stream>>>(x,ws);
  k_mlp<0> <<<dim3(512),dim3(512),0,stream>>>(x,w1,b1,w2,b2,w3,b3,ws);
  k_finB   <<<dim3(1),  dim3(256),0,stream>>>(gm2,be2,ws);
  k_spatial<<<dim3(512),dim3(256),0,stream>>>(x,ws);
  k_mlp<1> <<<dim3(512),dim3(512),0,stream>>>(x,w1,b1,w2,b2,w3,b3,ws);
  k_finC   <<<dim3(1),  dim3(512),0,stream>>>(gm3,be3,ws);
  k_mlp<2> <<<dim3(512),dim3(512),0,stream>>>(x,w1,b1,w2,b2,w3,b3,ws);
  k_final  <<<dim3(16), dim3(256),0,stream>>>(wp,bp,gln,bln,out,ws);
}